// Round 6
// baseline (162.049 us; speedup 1.0000x reference)
//
#include <hip/hip_runtime.h>

// GAT encoder: N=50000 nodes, E=800000 edges, H=4 heads, C=64 dims.
//
// Pipeline (all on `stream`, graph-capture safe):
//   memset(deg) -> precompute (fold att einsums to per-head scalars)
//   -> hist (degree histogram; atomic return value = per-edge rank)
//   -> scan1/scan2/scan3 (3-phase parallel exclusive prefix sum of deg)
//   -> scatter (counting-sort edges by dst; 4B packed entry src|ea_q16<<16)
//   -> gat (16 lanes/node, edges across lanes, 12-scalar factored reduction)
//
// R1: same-address float atomicAdd serialized ~33cyc/RMW = 170us -> partials.
// R2: single-block scan = 126us on one CU -> 3-phase grid-wide scan.
// R3: gat replicated per-edge work across 64 lanes (78us, VALU-bound) ->
//     factor msg into per-head (Sx,Sy,D); edges parallel across 16 lanes.
// R4: 160.6us; top-5 = harness 256MiB ws poison (44us, untouchable).
// R5 FAILED: 5-way batched change (pay packing, scan3 removal, precompute
//     fold, relayout, quantization) diverged on graph replays only; cause
//     unattributed. Reverted to R4 structure wholesale.
// R6: R4 + ONE delta: sorted entries packed to 4B (src | ea_q16<<16).
//     Quantization numerics validated by R5's first launch (absmax 0.0156).

#define N_NODES 50000
#define N_EDGES 800000
#define HIST_BLOCKS (N_EDGES / 256)     // 3125
#define SCAN_BLOCKS 49                  // ceil(12500 int4 / 256)

// ---- workspace layout (bytes) ---- (identical to R4)
// scal float[32]: [0..7]=ws(h,k) [8..15]=wd(h,k) [16..19]=we(h) [20]=sum(ea)
constexpr size_t OFF_SCAL = 0;
constexpr size_t OFF_PART = 128;       // float[3125]
constexpr size_t OFF_BSUM = 12800;     // int[64]
constexpr size_t OFF_BOFF = 13056;     // int[64]
constexpr size_t OFF_DEG  = 13312;     // int[N]        -> 213312
constexpr size_t OFF_ROW  = 213312;    // int[N+1]      -> 413316 (pad)
constexpr size_t OFF_CUR  = 413328;    // int[N]  (fallback path only)
constexpr size_t OFF_SORT = 613328;    // uint[E]       -> 3813328
constexpr size_t OFF_RANK = 7013328;   // int[E] (rank path) -> 10213328
constexpr size_t NEED_RANK = OFF_RANK + (size_t)N_EDGES * sizeof(int);

__global__ void precompute_kernel(const float* __restrict__ W,
                                  const float* __restrict__ att_src,
                                  const float* __restrict__ att_dst,
                                  const float* __restrict__ W_edge,
                                  const float* __restrict__ att_edge,
                                  float* __restrict__ scal) {
    int t = threadIdx.x;            // 0..255 = (h*64 + c)
    int h = t >> 6, lane = t & 63;
    float w0 = W[2 * t], w1 = W[2 * t + 1];
    float as = att_src[t], ad = att_dst[t];
    float ae = att_edge[t], wE = W_edge[t];
    float v0 = as * w0, v1 = as * w1, v2 = ad * w0, v3 = ad * w1, v4 = ae * wE;
    for (int off = 32; off; off >>= 1) {
        v0 += __shfl_down(v0, off, 64);
        v1 += __shfl_down(v1, off, 64);
        v2 += __shfl_down(v2, off, 64);
        v3 += __shfl_down(v3, off, 64);
        v4 += __shfl_down(v4, off, 64);
    }
    if (lane == 0) {
        scal[2 * h]     = v0;  scal[2 * h + 1] = v1;
        scal[8 + 2 * h] = v2;  scal[9 + 2 * h] = v3;
        scal[16 + h]    = v4;
    }
}

// E = 3125 * 256 exactly. Rank path: atomic return value = within-dst rank.
__global__ __launch_bounds__(256) void hist_rank_kernel(const int* __restrict__ ei,
                                                        const float* __restrict__ ea,
                                                        int* __restrict__ deg,
                                                        int* __restrict__ rank,
                                                        float* __restrict__ part) {
    __shared__ float sm[4];
    int e = blockIdx.x * 256 + threadIdx.x;
    rank[e] = atomicAdd(&deg[ei[N_EDGES + e]], 1);
    float v = ea[e];
    for (int off = 32; off; off >>= 1) v += __shfl_down(v, off, 64);
    if ((threadIdx.x & 63) == 0) sm[threadIdx.x >> 6] = v;
    __syncthreads();
    if (threadIdx.x == 0) part[blockIdx.x] = sm[0] + sm[1] + sm[2] + sm[3];
}

__global__ __launch_bounds__(256) void hist_kernel(const int* __restrict__ ei,
                                                   const float* __restrict__ ea,
                                                   int* __restrict__ deg,
                                                   float* __restrict__ part) {
    __shared__ float sm[4];
    int e = blockIdx.x * 256 + threadIdx.x;
    atomicAdd(&deg[ei[N_EDGES + e]], 1);
    float v = ea[e];
    for (int off = 32; off; off >>= 1) v += __shfl_down(v, off, 64);
    if ((threadIdx.x & 63) == 0) sm[threadIdx.x >> 6] = v;
    __syncthreads();
    if (threadIdx.x == 0) part[blockIdx.x] = sm[0] + sm[1] + sm[2] + sm[3];
}

// Phase 1: per-block scan. Each thread owns an int4 of deg (coalesced).
__global__ __launch_bounds__(256) void scan1_kernel(const int4* __restrict__ deg4,
                                                    int4* __restrict__ row4,
                                                    int* __restrict__ bsum) {
    __shared__ int sm[4];
    int t = threadIdx.x, lane = t & 63, w = t >> 6;
    int gid = blockIdx.x * 256 + t;
    int4 d = make_int4(0, 0, 0, 0);
    if (gid < 12500) d = deg4[gid];
    int mysum = d.x + d.y + d.z + d.w;
    int s = mysum;
    for (int off = 1; off < 64; off <<= 1) {
        int v = __shfl_up(s, off, 64);
        if (lane >= off) s += v;
    }
    if (lane == 63) sm[w] = s;
    __syncthreads();
    int woff = 0;
    for (int i = 0; i < 4; ++i) if (i < w) woff += sm[i];
    int base = woff + s - mysum;          // block-local exclusive prefix
    if (gid < 12500) {
        int4 r;
        r.x = base;
        r.y = r.x + d.x;
        r.z = r.y + d.y;
        r.w = r.z + d.z;
        row4[gid] = r;
    }
    if (t == 0) bsum[blockIdx.x] = sm[0] + sm[1] + sm[2] + sm[3];
}

// Phase 2: scan 49 block sums; reduce ea partials -> scal[20]; row[N]=E.
__global__ __launch_bounds__(256) void scan2_kernel(const int* __restrict__ bsum,
                                                    const float* __restrict__ part,
                                                    int* __restrict__ boff,
                                                    int* __restrict__ row_start,
                                                    float* __restrict__ scal) {
    __shared__ float sf[4];
    int t = threadIdx.x, lane = t & 63;
    float v = 0.0f;
    for (int i = t; i < HIST_BLOCKS; i += 256) v += part[i];
    for (int off = 32; off; off >>= 1) v += __shfl_down(v, off, 64);
    if (lane == 0) sf[t >> 6] = v;
    __syncthreads();
    if (t == 0) scal[20] = sf[0] + sf[1] + sf[2] + sf[3];

    if (t < 64) {
        int s = (lane < SCAN_BLOCKS) ? bsum[lane] : 0;
        int own = s;
        for (int off = 1; off < 64; off <<= 1) {
            int x = __shfl_up(s, off, 64);
            if (lane >= off) s += x;
        }
        if (lane < SCAN_BLOCKS) boff[lane] = s - own;   // exclusive
        if (lane == SCAN_BLOCKS - 1) row_start[N_NODES] = s;
    }
}

// Phase 3: add block offsets (cur4 only used by fallback path).
__global__ __launch_bounds__(256) void scan3_kernel(const int* __restrict__ boff,
                                                    int4* __restrict__ row4,
                                                    int4* __restrict__ cur4) {
    int gid = blockIdx.x * 256 + threadIdx.x;
    if (gid >= 12500) return;
    int o = boff[blockIdx.x];
    int4 r = row4[gid];
    r.x += o; r.y += o; r.z += o; r.w += o;
    row4[gid] = r;
    if (cur4) cur4[gid] = r;
}

// Rank path: atomic-free scatter. Entry packed: src | ea_q16<<16.
__global__ __launch_bounds__(256) void scatter_rank_kernel(
        const int* __restrict__ ei, const float* __restrict__ ea,
        const int* __restrict__ rank, const int* __restrict__ row_start,
        unsigned* __restrict__ sorted) {
    int e = blockIdx.x * 256 + threadIdx.x;
    int src = ei[e], dst = ei[N_EDGES + e];
    unsigned eaq = (unsigned)(ea[e] * 65535.0f + 0.5f);
    sorted[row_start[dst] + rank[e]] = (unsigned)src | (eaq << 16);
}

// Fallback path: cursor atomics.
__global__ __launch_bounds__(256) void scatter_kernel(const int* __restrict__ ei,
                                                      const float* __restrict__ ea,
                                                      int* __restrict__ cursor,
                                                      unsigned* __restrict__ sorted) {
    int e = blockIdx.x * 256 + threadIdx.x;
    int src = ei[e], dst = ei[N_EDGES + e];
    unsigned eaq = (unsigned)(ea[e] * 65535.0f + 0.5f);
    int pos = atomicAdd(&cursor[dst], 1);
    sorted[pos] = (unsigned)src | (eaq << 16);
}

// 16 lanes per node, 16 nodes per block, grid = 3125 (exact).
// Per edge (one lane each): 4 heads of (alpha, exp) -> (D,Sx,Sy) per head;
// butterfly-reduce across the 16-lane group; coalesced float4 epilogue.
__global__ __launch_bounds__(256) void gat_kernel(
        const float2* __restrict__ x2, const float4* __restrict__ W4,
        const float* __restrict__ scal, const int* __restrict__ row_start,
        const unsigned* __restrict__ sorted, const float4* __restrict__ bias4,
        float4* __restrict__ out4) {
    int t = threadIdx.x;
    int sub = t & 15;
    int node = blockIdx.x * 16 + (t >> 4);

    float ws0[4], ws1[4], wd0[4], wd1[4], we[4];
#pragma unroll
    for (int h = 0; h < 4; ++h) {
        ws0[h] = scal[2 * h];     ws1[h] = scal[2 * h + 1];
        wd0[h] = scal[8 + 2 * h]; wd1[h] = scal[9 + 2 * h];
        we[h]  = scal[16 + h];
    }
    float meanea = scal[20] * (1.0f / N_EDGES);

    float2 xd = x2[node];
    float adst[4];
#pragma unroll
    for (int h = 0; h < 4; ++h) adst[h] = xd.x * wd0[h] + xd.y * wd1[h];

    float D[4], Sx[4], Sy[4];
#pragma unroll
    for (int h = 0; h < 4; ++h) { D[h] = 0.0f; Sx[h] = 0.0f; Sy[h] = 0.0f; }

    if (sub == 0) {   // self loop (src = dst, ea = mean of original edges)
#pragma unroll
        for (int h = 0; h < 4; ++h) {
            float a = xd.x * ws0[h] + xd.y * ws1[h] + adst[h] + meanea * we[h];
            a = fmaxf(a, 0.2f * a);
            float ex = __expf(a);
            D[h] = ex; Sx[h] = ex * xd.x; Sy[h] = ex * xd.y;
        }
    }

    int rs = row_start[node], re = row_start[node + 1];
    for (int e = rs + sub; e < re; e += 16) {
        unsigned u = sorted[e];
        float2 xs = x2[u & 0xffffu];
        float eav = (float)(u >> 16) * (1.0f / 65535.0f);
#pragma unroll
        for (int h = 0; h < 4; ++h) {
            float a = xs.x * ws0[h] + xs.y * ws1[h] + adst[h] + eav * we[h];
            a = fmaxf(a, 0.2f * a);
            float ex = __expf(a);
            D[h] += ex; Sx[h] += ex * xs.x; Sy[h] += ex * xs.y;
        }
    }

#pragma unroll
    for (int m = 1; m < 16; m <<= 1) {
#pragma unroll
        for (int h = 0; h < 4; ++h) {
            D[h]  += __shfl_xor(D[h],  m, 16);
            Sx[h] += __shfl_xor(Sx[h], m, 16);
            Sy[h] += __shfl_xor(Sy[h], m, 16);
        }
    }

#pragma unroll
    for (int k = 0; k < 4; ++k) {
        int j = sub + 16 * k;
        float invD = 1.0f / D[k];
        float4 wa = W4[2 * j], wb = W4[2 * j + 1], b = bias4[j];
        float4 o;
        o.x = (wa.x * Sx[k] + wa.y * Sy[k]) * invD + b.x;
        o.y = (wa.z * Sx[k] + wa.w * Sy[k]) * invD + b.y;
        o.z = (wb.x * Sx[k] + wb.y * Sy[k]) * invD + b.z;
        o.w = (wb.z * Sx[k] + wb.w * Sy[k]) * invD + b.w;
        out4[node * 64 + j] = o;
    }
}

extern "C" void kernel_launch(void* const* d_in, const int* in_sizes, int n_in,
                              void* d_out, int out_size, void* d_ws, size_t ws_size,
                              hipStream_t stream) {
    const float* x        = (const float*)d_in[0];
    const int*   ei       = (const int*)  d_in[1];
    const float* ea       = (const float*)d_in[2];
    const float* W        = (const float*)d_in[3];
    const float* att_src  = (const float*)d_in[4];
    const float* att_dst  = (const float*)d_in[5];
    const float* W_edge   = (const float*)d_in[6];
    const float* att_edge = (const float*)d_in[7];
    const float* bias     = (const float*)d_in[8];

    char* ws = (char*)d_ws;
    float*    scal   = (float*)   (ws + OFF_SCAL);
    float*    part   = (float*)   (ws + OFF_PART);
    int*      bsum   = (int*)     (ws + OFF_BSUM);
    int*      boff   = (int*)     (ws + OFF_BOFF);
    int*      deg    = (int*)     (ws + OFF_DEG);
    int*      row_st = (int*)     (ws + OFF_ROW);
    int*      cursor = (int*)     (ws + OFF_CUR);
    int*      rank   = (int*)     (ws + OFF_RANK);
    unsigned* sorted = (unsigned*)(ws + OFF_SORT);

    const bool use_rank = (ws_size >= NEED_RANK);   // ws_size is call-invariant

    hipMemsetAsync(deg, 0, N_NODES * sizeof(int), stream);
    precompute_kernel<<<1, 256, 0, stream>>>(W, att_src, att_dst, W_edge, att_edge, scal);
    if (use_rank)
        hist_rank_kernel<<<HIST_BLOCKS, 256, 0, stream>>>(ei, ea, deg, rank, part);
    else
        hist_kernel<<<HIST_BLOCKS, 256, 0, stream>>>(ei, ea, deg, part);
    scan1_kernel<<<SCAN_BLOCKS, 256, 0, stream>>>((const int4*)deg, (int4*)row_st, bsum);
    scan2_kernel<<<1, 256, 0, stream>>>(bsum, part, boff, row_st, scal);
    scan3_kernel<<<SCAN_BLOCKS, 256, 0, stream>>>(boff, (int4*)row_st,
                                                  use_rank ? (int4*)nullptr : (int4*)cursor);
    if (use_rank)
        scatter_rank_kernel<<<HIST_BLOCKS, 256, 0, stream>>>(ei, ea, rank, row_st, sorted);
    else
        scatter_kernel<<<HIST_BLOCKS, 256, 0, stream>>>(ei, ea, cursor, sorted);
    gat_kernel<<<N_NODES / 16, 256, 0, stream>>>(
        (const float2*)x, (const float4*)W, scal, row_st, sorted,
        (const float4*)bias, (float4*)d_out);
}